// Round 17
// baseline (387.628 us; speedup 1.0000x reference)
//
#include <hip/hip_runtime.h>
#include <cstddef>

#define NN 1024
#define DD 6
#define TT 60
#define HH 64
#define NEGV  (-10000.0f)
#define SLOPEV (0.01f)
#define GRUB 64           // GRU blocks: 16 samples, 8 waves (512 thr)
#define RELB 192          // 64+192 = 256 blocks = exactly 1/CU (LDS-forced)
#define RELW (RELB * 8)   // rel waves total
#define NGRP (NN * NN / 64)

// LDS float offsets (GRU uses [0,7232); rest is padding that forces 1 block/CU)
#define BH0O  0           // h0 f16, 2 parities x [n][36]  (1152 floats)
#define BH1O  1152        // h1 f16, 2 parities x [n][36]
#define XH    2304        // x f16 [(t*16+n)*4 floats]     (3840)
#define HEP   6144        // h1 f32 epilogue staging [j][17] (1088)
#define SMEMF 20608       // 82.4 KB > 80 KB -> hardware caps at 1 block/CU:
                          // 64 GRU blocks get private CUs (uncontended serial
                          // chain); 192 rel blocks get 192 CUs. R13-R16 all
                          // pinned at k_main~125us with 2 blocks/CU mixing
                          // roles — contention, not BW or structure.

typedef _Float16 v8h __attribute__((ext_vector_type(8)));
typedef float    v4f __attribute__((ext_vector_type(4)));

#define MF(a, b, c) __builtin_amdgcn_mfma_f32_16x16x32_f16((a), (b), (c), 0, 0, 0)

__device__ __forceinline__ float sig_(float x)  { return 1.0f / (1.0f + __expf(-x)); }
__device__ __forceinline__ float tanh_(float x) { return 1.0f - 2.0f / (__expf(2.0f * x) + 1.0f); }
__device__ __forceinline__ float bcf_(const float a, const float b) {
    return __builtin_bit_cast(float, __builtin_amdgcn_cvt_pkrtz(a, b));
}
__device__ __forceinline__ v8h zero8() {
    v8h r;
    #pragma unroll
    for (int j = 0; j < 8; ++j) r[j] = (_Float16)0.f;
    return r;
}
__device__ __forceinline__ v8h pack8(const float* __restrict__ p) {
    v8h r;
    #pragma unroll
    for (int j = 0; j < 8; ++j) r[j] = (_Float16)p[j];
    return r;
}
__device__ __forceinline__ v8h pack6(const float* __restrict__ p) {
    v8h r = zero8();
    #pragma unroll
    for (int j = 0; j < 6; ++j) r[j] = (_Float16)p[j];
    return r;
}

// ---------------------------------------------------------------------------
// k_main: 256 blocks x 512 threads, ONE block per CU (82 KB LDS pad).
//   blocks [0,64): MFMA GRU on 64 private CUs — in-register gate update,
//     one barrier/step, parity-dbuf f16 h exchange (R15-verified datapath).
//   blocks [64,256): rel streaming on 192 private CUs — coalesced 64-pair
//     groups, 16x 1KB wave loads, 16-lane shfl_xor reduce (R16 pattern).
// ---------------------------------------------------------------------------
__global__ __launch_bounds__(512)
void k_main(const float* __restrict__ x, const float* __restrict__ rel,
            const float* __restrict__ W, const float* __restrict__ fc_w,
            const float* __restrict__ Wih0, const float* __restrict__ Whh0,
            const float* __restrict__ bih0, const float* __restrict__ bhh0,
            const float* __restrict__ Wih1, const float* __restrict__ Whh1,
            const float* __restrict__ bih1, const float* __restrict__ bhh1,
            float* __restrict__ sa, float* __restrict__ sb,
            float* __restrict__ hdot, float* __restrict__ hb,
            float* __restrict__ sr, float* __restrict__ ssum)
{
    __shared__ float smem[SMEMF];
    const int tid = threadIdx.x;

    if (blockIdx.x >= GRUB) {
        // ---------------- relation streaming (dedicated CUs) ----------------
        const int lane = tid & 63;
        const int l16  = lane & 15;
        const int sub  = lane >> 4;
        const float4 wv4 = *(const float4*)(W + 2 * HH + l16 * 4);
        const unsigned wid = (unsigned)(blockIdx.x - GRUB) * 8 + (tid >> 6);
        for (unsigned g = wid; g < (unsigned)NGRP; g += RELW) {
            const float4* bp = (const float4*)(rel + (size_t)g * 4096) + lane;
            float4 v[16];
            #pragma unroll
            for (int q = 0; q < 16; ++q) v[q] = bp[q * 64];   // 1 KB contiguous / load
            float dt[16], sm[16];
            #pragma unroll
            for (int q = 0; q < 16; ++q) {
                dt[q] = v[q].x * wv4.x + v[q].y * wv4.y + v[q].z * wv4.z + v[q].w * wv4.w;
                sm[q] = (v[q].x + v[q].y) + (v[q].z + v[q].w);
            }
            #pragma unroll
            for (int m = 1; m <= 8; m <<= 1) {
                #pragma unroll
                for (int q = 0; q < 16; ++q) {
                    dt[q] += __shfl_xor(dt[q], m);
                    sm[q] += __shfl_xor(sm[q], m);
                }
            }
            if (l16 == 0) {
                #pragma unroll
                for (int q = 0; q < 16; ++q) {
                    const unsigned p = g * 64 + q * 4 + sub;
                    sr[p]   = dt[q];
                    ssum[p] = sm[q];
                }
            }
        }
        return;
    }

    // ---------------- GRU (unchanged, R15-verified) ----------------
    const int w    = tid >> 6;          // wave 0..7
    const int lane = tid & 63;
    const int quad = lane >> 4;
    const int mc   = lane & 15;
    const int nb   = blockIdx.x * 16;
    const bool isL0 = (w < 4);
    const int wt   = isL0 ? w : (w - 4);   // row-tile index within layer

    // ---- stage x as f16; zero both parities of BH0/BH1 ----
    for (int idx = tid; idx < TT * 16; idx += 512) {
        const int t = idx >> 4, n = idx & 15;
        const float* xp = x + (size_t)(nb + n) * (DD * TT) + t;
        float4 pk;
        pk.x = bcf_(xp[0],   xp[60]);
        pk.y = bcf_(xp[120], xp[180]);
        pk.z = bcf_(xp[240], xp[300]);
        pk.w = 0.f;
        *(float4*)(smem + XH + idx * 4) = pk;
    }
    for (int idx = tid; idx < 2304; idx += 512) smem[idx] = 0.f;

    // ---- persistent A-fragments ----
    const int r0row = 16 * wt + mc;
    const int zrow  = 64 + 16 * wt + mc;
    const int nrow  = 128 + 16 * wt + mc;
    v8h F0 = zero8(), F1 = zero8(), F2 = zero8(), F3 = zero8();
    v8h F4 = zero8(), F5 = zero8(), F6 = zero8(), F7 = zero8();
    v8h F8 = zero8(), F9 = zero8(), F10 = zero8(), F11 = zero8();
    v8h Xr = zero8(), Xz = zero8(), Xn = zero8();
    if (isL0) {
        F0 = pack8(Whh0 + (size_t)r0row * HH + quad * 8);         // Ar0
        F1 = pack8(Whh0 + (size_t)r0row * HH + 32 + quad * 8);    // Ar1
        F2 = pack8(Whh0 + (size_t)zrow  * HH + quad * 8);         // Az0
        F3 = pack8(Whh0 + (size_t)zrow  * HH + 32 + quad * 8);    // Az1
        F4 = pack8(Whh0 + (size_t)nrow  * HH + quad * 8);         // An0
        F5 = pack8(Whh0 + (size_t)nrow  * HH + 32 + quad * 8);    // An1
        if (quad == 0) {
            Xr = pack6(Wih0 + r0row * DD);
            Xz = pack6(Wih0 + zrow  * DD);
            Xn = pack6(Wih0 + nrow  * DD);
        }
    } else {
        F0 = pack8(Wih1 + (size_t)r0row * HH + quad * 8);         // R0
        F1 = pack8(Wih1 + (size_t)r0row * HH + 32 + quad * 8);    // R1
        F2 = pack8(Whh1 + (size_t)r0row * HH + quad * 8);         // R2
        F3 = pack8(Whh1 + (size_t)r0row * HH + 32 + quad * 8);    // R3
        F4 = pack8(Wih1 + (size_t)zrow * HH + quad * 8);          // Z0
        F5 = pack8(Wih1 + (size_t)zrow * HH + 32 + quad * 8);     // Z1
        F6 = pack8(Whh1 + (size_t)zrow * HH + quad * 8);          // Z2
        F7 = pack8(Whh1 + (size_t)zrow * HH + 32 + quad * 8);     // Z3
        F8 = pack8(Wih1 + (size_t)nrow * HH + quad * 8);          // Nx0
        F9 = pack8(Wih1 + (size_t)nrow * HH + 32 + quad * 8);     // Nx1
        F10 = pack8(Whh1 + (size_t)nrow * HH + quad * 8);         // Nh0
        F11 = pack8(Whh1 + (size_t)nrow * HH + 32 + quad * 8);    // Nh1
    }

    // ---- biases at C rows (lane's 4 rows = 16wt + quad*4 + e) ----
    float bR[4], bZ[4], bXn[4], bHn[4];
    #pragma unroll
    for (int e = 0; e < 4; ++e) {
        const int cr = 16 * wt + quad * 4 + e;
        if (isL0) {
            bR[e]  = bih0[cr] + bhh0[cr];
            bZ[e]  = bih0[64 + cr] + bhh0[64 + cr];
            bXn[e] = bih0[128 + cr];
            bHn[e] = bhh0[128 + cr];
        } else {
            bR[e]  = bih1[cr] + bhh1[cr];
            bZ[e]  = bih1[64 + cr] + bhh1[64 + cr];
            bXn[e] = bih1[128 + cr];
            bHn[e] = bhh1[128 + cr];
        }
    }

    float hp[4] = {0.f, 0.f, 0.f, 0.f};   // persistent h[j=16wt+quad*4+e][n=mc]
    __syncthreads();

    auto ldb = [&](const float* basep, int win) -> v8h {
        return __builtin_bit_cast(v8h,
            *(const float4*)(basep + mc * 36 + win * 16 + quad * 4));
    };
    auto sth = [&](float* basep) {
        float2 pk;
        pk.x = bcf_(hp[0], hp[1]);
        pk.y = bcf_(hp[2], hp[3]);
        *(float2*)(basep + mc * 36 + 8 * wt + 2 * quad) = pk;
    };
    auto gupd = [&](const v4f& cr, const v4f& cz, const v4f& cx, const v4f& ch) {
        #pragma unroll
        for (int e = 0; e < 4; ++e) {
            const float r  = sig_(cr[e]);
            const float z  = sig_(cz[e]);
            const float nv = tanh_(cx[e] + r * ch[e]);
            hp[e] = (1.f - z) * nv + z * hp[e];
        }
    };

    for (int i = 0; i <= TT; ++i) {
        const int rbo = (i & 1) * 576;          // read parity
        const int wbo = 576 - rbo;              // write parity
        if (isL0) {
            if (i < TT) {
                const v8h b0 = ldb(smem + BH0O + rbo, 0);
                const v8h b1 = ldb(smem + BH0O + rbo, 1);
                const float4 xl = *(const float4*)(smem + XH + (i * 16 + mc) * 4);
                v8h bx = zero8();
                if (quad == 0) bx = __builtin_bit_cast(v8h, xl);

                v4f cr = {bR[0], bR[1], bR[2], bR[3]};
                cr = MF(F0, b0, cr); cr = MF(F1, b1, cr); cr = MF(Xr, bx, cr);
                v4f cz = {bZ[0], bZ[1], bZ[2], bZ[3]};
                cz = MF(F2, b0, cz); cz = MF(F3, b1, cz); cz = MF(Xz, bx, cz);
                v4f ch = {bHn[0], bHn[1], bHn[2], bHn[3]};
                ch = MF(F4, b0, ch); ch = MF(F5, b1, ch);
                v4f cx = {bXn[0], bXn[1], bXn[2], bXn[3]};
                cx = MF(Xn, bx, cx);

                gupd(cr, cz, cx, ch);
                sth(smem + BH0O + wbo);
            }
        } else {
            if (i >= 1) {
                const v8h g0 = ldb(smem + BH0O + rbo, 0);   // h0 after t=i-1
                const v8h g1 = ldb(smem + BH0O + rbo, 1);
                const v8h g2 = ldb(smem + BH1O + rbo, 0);   // h1 after t=i-2
                const v8h g3 = ldb(smem + BH1O + rbo, 1);

                v4f cr = {bR[0], bR[1], bR[2], bR[3]};
                cr = MF(F0, g0, cr); cr = MF(F1, g1, cr);
                cr = MF(F2, g2, cr); cr = MF(F3, g3, cr);
                v4f cz = {bZ[0], bZ[1], bZ[2], bZ[3]};
                cz = MF(F4, g0, cz); cz = MF(F5, g1, cz);
                cz = MF(F6, g2, cz); cz = MF(F7, g3, cz);
                v4f cx = {bXn[0], bXn[1], bXn[2], bXn[3]};
                cx = MF(F8, g0, cx); cx = MF(F9, g1, cx);
                v4f ch = {bHn[0], bHn[1], bHn[2], bHn[3]};
                ch = MF(F10, g2, ch); ch = MF(F11, g3, ch);

                gupd(cr, cz, cx, ch);
                sth(smem + BH1O + wbo);
            }
        }
        __syncthreads();
    }

    // ---------------- epilogue ----------------
    if (!isL0) {
        #pragma unroll
        for (int e = 0; e < 4; ++e)
            smem[HEP + (16 * wt + quad * 4 + e) * 17 + mc] = hp[e];
    }
    __syncthreads();
    if (isL0) {
        const int n = lane >> 2, p = lane & 3;
        const float* __restrict__ wp = (w == 0) ? W : (w == 1) ? (W + HH)
                                     : (w == 2) ? fc_w : (fc_w + HH);
        float v = 0.f;
        #pragma unroll
        for (int q = 0; q < 16; ++q) {
            const int j = p * 16 + q;
            v += smem[HEP + j * 17 + n] * wp[j];
        }
        v += __shfl_down(v, 2);
        v += __shfl_down(v, 1);
        if (p == 0) {
            float* dst = (w == 0) ? sa : (w == 1) ? sb : (w == 2) ? hdot : hb;
            dst[nb + n] = v;
        }
    }
}

// ---------------------------------------------------------------------------
// k2: per row i — masked leaky scores, exact masked-softmax semantics,
// out_i = hdot_i + (sum_j e_j*m_j*hb_j)/denom + fc_b.   (verified R2-R16)
// ---------------------------------------------------------------------------
__global__ __launch_bounds__(256)
void k2(const float* __restrict__ sa, const float* __restrict__ sb,
        const float* __restrict__ hdot, const float* __restrict__ hb,
        const float* __restrict__ sr, const float* __restrict__ ssum,
        const float* __restrict__ bscal, const float* __restrict__ fc_b,
        float* __restrict__ out)
{
    __shared__ float red[12];
    const int i   = blockIdx.x;
    const int tid = threadIdx.x;
    const int j4  = tid * 4;
    const float sai = sa[i] + bscal[0];

    const float4 srv = *(const float4*)(sr   + (size_t)i * NN + j4);
    const float4 ssv = *(const float4*)(ssum + (size_t)i * NN + j4);
    const float4 sbv = *(const float4*)(sb + j4);

    float tv[4], mk[4];
    float mloc = -3.4e38f;
    {
        const float srq[4] = {srv.x, srv.y, srv.z, srv.w};
        const float ssq[4] = {ssv.x, ssv.y, ssv.z, ssv.w};
        const float sbq[4] = {sbv.x, sbv.y, sbv.z, sbv.w};
        #pragma unroll
        for (int q = 0; q < 4; ++q) {
            float wv = sai + sbq[q] + srq[q];
            wv = (wv >= 0.0f) ? wv : SLOPEV * wv;
            const float m = (ssq[q] != 0.0f) ? 1.0f : 0.0f;
            float tt = m * wv;
            tt = (tt == 0.0f) ? NEGV : tt;
            tv[q] = tt; mk[q] = m;
            mloc = fmaxf(mloc, tt);
        }
    }
    #pragma unroll
    for (int off = 32; off >= 1; off >>= 1) mloc = fmaxf(mloc, __shfl_xor(mloc, off));
    if ((tid & 63) == 0) red[tid >> 6] = mloc;
    __syncthreads();
    const float mx = fmaxf(fmaxf(red[0], red[1]), fmaxf(red[2], red[3]));

    const float4 hbv = *(const float4*)(hb + j4);
    const float hbq[4] = {hbv.x, hbv.y, hbv.z, hbv.w};
    float sloc = 0.0f, vloc = 0.0f;
    #pragma unroll
    for (int q = 0; q < 4; ++q) {
        const float e = __expf(tv[q] - mx);   // masked -> exp(-1e4 - mx) == 0
        sloc += e;
        vloc += e * mk[q] * hbq[q];
    }
    #pragma unroll
    for (int off = 32; off >= 1; off >>= 1) {
        sloc += __shfl_xor(sloc, off);
        vloc += __shfl_xor(vloc, off);
    }
    if ((tid & 63) == 0) { red[4 + (tid >> 6)] = sloc; red[8 + (tid >> 6)] = vloc; }
    __syncthreads();
    if (tid == 0) {
        const float denom = red[4] + red[5] + red[6] + red[7];
        const float vsum  = red[8] + red[9] + red[10] + red[11];
        out[i] = hdot[i] + vsum / denom + fc_b[0];
    }
}

// ---------------------------------------------------------------------------
extern "C" void kernel_launch(void* const* d_in, const int* in_sizes, int n_in,
                              void* d_out, int out_size, void* d_ws, size_t ws_size,
                              hipStream_t stream)
{
    const float* x     = (const float*)d_in[0];
    const float* rel   = (const float*)d_in[1];
    const float* W     = (const float*)d_in[2];
    const float* b     = (const float*)d_in[3];
    const float* fc_w  = (const float*)d_in[4];
    const float* fc_b  = (const float*)d_in[5];
    const float* Wih0  = (const float*)d_in[6];
    const float* Whh0  = (const float*)d_in[7];
    const float* bih0  = (const float*)d_in[8];
    const float* bhh0  = (const float*)d_in[9];
    const float* Wih1  = (const float*)d_in[10];
    const float* Whh1  = (const float*)d_in[11];
    const float* bih1  = (const float*)d_in[12];
    const float* bhh1  = (const float*)d_in[13];

    float* ws   = (float*)d_ws;
    float* sa   = ws;                         // 1024
    float* sb   = sa   + NN;                  // 1024
    float* hdot = sb   + NN;                  // 1024
    float* hb   = hdot + NN;                  // 1024
    float* sr   = hb   + NN;                  // 1024*1024
    float* ssum = sr   + (size_t)NN * NN;     // 1024*1024

    k_main<<<GRUB + RELB, 512, 0, stream>>>(x, rel, W, fc_w,
                                            Wih0, Whh0, bih0, bhh0,
                                            Wih1, Whh1, bih1, bhh1,
                                            sa, sb, hdot, hb, sr, ssum);
    k2<<<NN, 256, 0, stream>>>(sa, sb, hdot, hb, sr, ssum,
                               b, fc_b, (float*)d_out);
}